// Round 6
// baseline (303.060 us; speedup 1.0000x reference)
//
#include <hip/hip_runtime.h>

// AllInOneFlow: y = perm-scatter( scale * concat(x1, x2*exp(ls)+off) + goff ), log_jac
// MLP 32->256->256->64 (gelu,gelu,linear), B=131072. bf16-split (3-product) MFMA.
// This rev: 32-row/4-wave/32KiB blocks (de-convoy, 4-5 blocks/CU), 32x32x16 MFMA
// (halves LDS frag reads), split-K GEMM3, shfl-bpermute epilogue (no LDS round-trip).
// FIX vs r5: LO_OFF 16384 -> 8192 (h_hi is 32x256 u16; old value wrote past LDS end).

#define NB  131072
#define DD  64
#define HH  256

typedef float f32x4 __attribute__((ext_vector_type(4)));
typedef float f32x16 __attribute__((ext_vector_type(16)));
typedef short bf16x8 __attribute__((ext_vector_type(8)));
typedef unsigned short u16;
typedef unsigned int u32;
typedef u32 u32x2 __attribute__((ext_vector_type(2)));

__device__ __align__(16) u16 g_w1h[32 * 256],  g_w1l[32 * 256];   // [n][k] n<256,k<32
__device__ __align__(16) u16 g_w2h[256 * 256], g_w2l[256 * 256];  // [n][k] 256x256
__device__ __align__(16) u16 g_w3h[64 * 256],  g_w3l[64 * 256];   // [n][k] n<64,k<256
__device__ __align__(16) int g_invp[64];
__device__ float g_egls[64];
__device__ float g_sgls;

__device__ __forceinline__ u16 f2bf(float x) {
  u32 u = __float_as_uint(x);
  u32 r = u + 0x7FFFu + ((u >> 16) & 1u); // RNE
  return (u16)(r >> 16);
}
__device__ __forceinline__ float bf2f(u16 b) {
  return __uint_as_float(((u32)b) << 16);
}
__device__ __forceinline__ u32 pk2(float a, float b) { // packed 2x f32->bf16 RNE
  u32 r;
  asm("v_cvt_pk_bf16_f32 %0, %1, %2" : "=v"(r) : "v"(a), "v"(b));
  return r;
}
__device__ __forceinline__ float fast_tanh(float z) {
  float e = __expf(2.0f * z);
  return 1.0f - 2.0f * __builtin_amdgcn_rcpf(e + 1.0f);
}
__device__ __forceinline__ float gelu_tanh(float x) {
  float u = x * x;
  float inner = x * (0.7978845608028654f + 0.03567740814183556f * u);
  return 0.5f * x * (1.0f + fast_tanh(inner));
}
__device__ __forceinline__ void split8(const float* v, bf16x8& hi, bf16x8& lo) {
  u32* hw = (u32*)&hi; u32* lw = (u32*)&lo;
#pragma unroll
  for (int j = 0; j < 4; ++j) {
    float a = v[2 * j], b = v[2 * j + 1];
    u32 p = pk2(a, b);
    float la = a - __uint_as_float(p << 16);
    float lb = b - __uint_as_float(p & 0xffff0000u);
    hw[j] = p; lw[j] = pk2(la, lb);
  }
}

#define MFMA32(a, b, c) __builtin_amdgcn_mfma_f32_32x32x16_bf16((a), (b), (c), 0, 0, 0)
#define LO_OFF 8192  // u16 offset of lo array: h_hi is 32*256 = 8192 u16 (16 KiB)

// gelu + split-once + b64 stores of 4 consecutive n at row m (hi and lo arrays).
// XOR swizzle on n (bits 3-5 ^ m&7); same involution applied on k at read time.
__device__ __forceinline__ void store_h4(u16* hb, int m, int n0, f32x4 accv) {
  float g0 = gelu_tanh(accv[0]), g1 = gelu_tanh(accv[1]);
  float g2 = gelu_tanh(accv[2]), g3 = gelu_tanh(accv[3]);
  u32 h01 = pk2(g0, g1), h23 = pk2(g2, g3);
  float l0 = g0 - __uint_as_float(h01 << 16);
  float l1 = g1 - __uint_as_float(h01 & 0xffff0000u);
  float l2 = g2 - __uint_as_float(h23 << 16);
  float l3 = g3 - __uint_as_float(h23 & 0xffff0000u);
  u32 l01 = pk2(l0, l1), l23 = pk2(l2, l3);
  int idx = (m << 8) + (n0 ^ ((m & 7) << 3));
  *(u32x2*)(hb + idx) = u32x2{h01, h23};
  *(u32x2*)(hb + idx + LO_OFF) = u32x2{l01, l23};
}

// ---------------- prep: LDS-tiled transpose, coalesced both sides ----------------
__global__ void flow_prep(const float* __restrict__ W1, const float* __restrict__ W2,
                          const float* __restrict__ W3, const int* __restrict__ perm,
                          const float* __restrict__ gin) {
  __shared__ float t[64][65];
  const int b = blockIdx.x, tid = threadIdx.x;
  if (b < 16) { // W2 [256k][256n]: tile kt,nt of 64x64
    int kt = (b & 3) * 64, nt = (b >> 2) * 64;
#pragma unroll
    for (int it = 0; it < 16; ++it) {
      int idx = it * 256 + tid, r = idx >> 6, c = idx & 63;
      t[r][c] = W2[(kt + r) * 256 + nt + c];
    }
    __syncthreads();
#pragma unroll
    for (int it = 0; it < 16; ++it) {
      int idx = it * 256 + tid, cc = idx >> 6, rr = idx & 63;
      float v = t[rr][cc];
      u16 h = f2bf(v);
      g_w2h[(nt + cc) * 256 + kt + rr] = h;
      g_w2l[(nt + cc) * 256 + kt + rr] = f2bf(v - bf2f(h));
    }
  } else if (b < 20) { // W1 [32k][256n]: n-tile of 64
    int nt = (b - 16) * 64;
#pragma unroll
    for (int it = 0; it < 8; ++it) {
      int idx = it * 256 + tid, r = idx >> 6, c = idx & 63;
      t[r][c] = W1[r * 256 + nt + c];
    }
    __syncthreads();
#pragma unroll
    for (int it = 0; it < 8; ++it) {
      int idx = it * 256 + tid, cc = idx >> 5, rr = idx & 31;
      float v = t[rr][cc];
      u16 h = f2bf(v);
      g_w1h[(nt + cc) * 32 + rr] = h;
      g_w1l[(nt + cc) * 32 + rr] = f2bf(v - bf2f(h));
    }
  } else if (b < 24) { // W3 [256k][64n]: k-tile of 64
    int kt = (b - 20) * 64;
#pragma unroll
    for (int it = 0; it < 16; ++it) {
      int idx = it * 256 + tid, r = idx >> 6, c = idx & 63;
      t[r][c] = W3[(kt + r) * 64 + c];
    }
    __syncthreads();
#pragma unroll
    for (int it = 0; it < 16; ++it) {
      int idx = it * 256 + tid, cc = idx >> 6, rr = idx & 63;
      float v = t[rr][cc];
      u16 h = f2bf(v);
      g_w3h[cc * 256 + kt + rr] = h;
      g_w3l[cc * 256 + kt + rr] = f2bf(v - bf2f(h));
    }
  } else { // perm, inv perm, global scale
    if (tid < 64) {
      int tt = tid;
      g_invp[perm[tt]] = tt;
      float gl = 4.0f * tanhf(gin[tt] * 0.25f);
      g_egls[tt] = expf(gl);
      float s = gl;
#pragma unroll
      for (int m = 1; m < 64; m <<= 1) s += __shfl_xor(s, m);
      if (tt == 0) g_sgls = s;
    }
  }
}

// ---------------- main: 32 rows/block, 4 waves, 32 KiB LDS ----------------
// LDS overlays (time-multiplexed): x-stage f32[32][68] (8.7KB) -> h_hi/h_lo
// bf16[32][256] (16KB + 16KB) -> params f32 P0/P1 at 0 / 2176 floats (17.4KB).
// MFMA 32x32x16, A = weight [n][k], B = activation [k][m] -> D[n][m]:
// lane holds col m = lane&31, rows n = (reg&3) + 8*(reg>>2) + 4*(lane>>5).
__global__ __launch_bounds__(256, 4) void flow_main(
    const float* __restrict__ x, const int* __restrict__ perm,
    const float* __restrict__ b1, const float* __restrict__ b2,
    const float* __restrict__ b3, const float* __restrict__ goff,
    float* __restrict__ out) {
  __shared__ u32 lds32[8192]; // 32 KiB exactly -> up to 5 blocks/CU by LDS
  u16* hb = (u16*)lds32;
  float* ldsf = (float*)lds32;
  const int tid = threadIdx.x;
  const int wave = tid >> 6, lane = tid & 63;
  const int a = lane & 31, hf = lane >> 5;
  const size_t row0 = (size_t)blockIdx.x * 32;

  // Phase A: stage x (32x64 f32), stride 68
  {
    const float4* xv = (const float4*)(x + row0 * DD);
#pragma unroll
    for (int t = 0; t < 2; ++t) {
      int i = tid + t * 256;
      int r = i >> 4, c4 = i & 15;
      float4 v = xv[i];
      *(float4*)(ldsf + r * 68 + c4 * 4) = v;
    }
  }
  __syncthreads();

  // Phase B: GEMM1 B-frags (inverse-perm gather of x1, k in [0,32)) + epilogue
  // x regs (lane j owns final col j: xp[r][j] = x[r][invp[j]] for its 8 rows).
  bf16x8 bxh[2], bxl[2];
#pragma unroll
  for (int kk = 0; kk < 2; ++kk) {
    float v[8];
#pragma unroll
    for (int j = 0; j < 8; ++j) v[j] = ldsf[a * 68 + g_invp[kk * 16 + hf * 8 + j]];
    split8(v, bxh[kk], bxl[kk]);
  }
  float xreg[8];
  {
    int cj = g_invp[lane];
#pragma unroll
    for (int rr = 0; rr < 8; ++rr) xreg[rr] = ldsf[(wave * 8 + rr) * 68 + cj];
  }
  __syncthreads(); // x-stage dead; region becomes h_hi/h_lo

  // Phase C: GEMM1 (K=32, M=32, N=256). Wave owns n-tiles {2w, 2w+1} (32 cols each).
#pragma unroll
  for (int c = 0; c < 2; ++c) {
    int nt = wave * 2 + c;
    f32x16 acc;
#pragma unroll
    for (int r2 = 0; r2 < 4; ++r2) {
      f32x4 bi = *(const f32x4*)(b1 + nt * 32 + r2 * 8 + hf * 4);
#pragma unroll
      for (int i = 0; i < 4; ++i) acc[r2 * 4 + i] = bi[i];
    }
#pragma unroll
    for (int kk = 0; kk < 2; ++kk) {
      int off = (nt * 32 + a) * 32 + kk * 16 + hf * 8;
      bf16x8 wh = *(const bf16x8*)(g_w1h + off);
      bf16x8 wl = *(const bf16x8*)(g_w1l + off);
      acc = MFMA32(wh, bxh[kk], acc);
      acc = MFMA32(wh, bxl[kk], acc);
      acc = MFMA32(wl, bxh[kk], acc);
    }
#pragma unroll
    for (int r2 = 0; r2 < 4; ++r2) {
      f32x4 run = {acc[r2 * 4], acc[r2 * 4 + 1], acc[r2 * 4 + 2], acc[r2 * 4 + 3]};
      store_h4(hb, a, nt * 32 + r2 * 8 + hf * 4, run);
    }
  }
  __syncthreads();

  // Phase D: GEMM2 (K=256, M=32, N=256). Wave owns n-tiles {2w, 2w+1};
  // B-frags (h1, LDS b128) shared across the two n-tiles.
  f32x16 acc2[2];
#pragma unroll
  for (int c = 0; c < 2; ++c)
#pragma unroll
    for (int r2 = 0; r2 < 4; ++r2) {
      f32x4 bi = *(const f32x4*)(b2 + (wave * 2 + c) * 32 + r2 * 8 + hf * 4);
#pragma unroll
      for (int i = 0; i < 4; ++i) acc2[c][r2 * 4 + i] = bi[i];
    }
  const int swz = (a & 7) << 3;
#pragma unroll
  for (int kk = 0; kk < 16; ++kk) {
    int koff = (kk * 16 + hf * 8) ^ swz;
    const u16* p = hb + (a << 8) + koff;
    bf16x8 bh = *(const bf16x8*)p;
    bf16x8 bl = *(const bf16x8*)(p + LO_OFF);
#pragma unroll
    for (int c = 0; c < 2; ++c) {
      int off = ((wave * 2 + c) * 32 + a) * 256 + kk * 16 + hf * 8;
      bf16x8 wh = *(const bf16x8*)(g_w2h + off);
      bf16x8 wl = *(const bf16x8*)(g_w2l + off);
      acc2[c] = MFMA32(wh, bh, acc2[c]);
      acc2[c] = MFMA32(wh, bl, acc2[c]);
      acc2[c] = MFMA32(wl, bh, acc2[c]);
    }
  }
  __syncthreads(); // all h1 reads done before overwrite
#pragma unroll
  for (int c = 0; c < 2; ++c)
#pragma unroll
    for (int r2 = 0; r2 < 4; ++r2) {
      f32x4 run = {acc2[c][r2 * 4], acc2[c][r2 * 4 + 1],
                   acc2[c][r2 * 4 + 2], acc2[c][r2 * 4 + 3]};
      store_h4(hb, a, (wave * 2 + c) * 32 + r2 * 8 + hf * 4, run);
    }
  __syncthreads();

  // Phase F: GEMM3 (K=256, M=32, N=64), split-K: wave = (n-tile nb3, k-half kh).
  const int nb3 = wave & 1, kh = wave >> 1;
  f32x16 acc3;
#pragma unroll
  for (int r2 = 0; r2 < 4; ++r2) {
    if (kh == 0) {
      f32x4 bi = *(const f32x4*)(b3 + nb3 * 32 + r2 * 8 + hf * 4);
#pragma unroll
      for (int i = 0; i < 4; ++i) acc3[r2 * 4 + i] = bi[i];
    } else {
#pragma unroll
      for (int i = 0; i < 4; ++i) acc3[r2 * 4 + i] = 0.0f;
    }
  }
#pragma unroll
  for (int kk = 0; kk < 8; ++kk) {
    int kbase = kh * 128 + kk * 16 + hf * 8;
    int koff = kbase ^ swz;
    const u16* p = hb + (a << 8) + koff;
    bf16x8 bh = *(const bf16x8*)p;
    bf16x8 bl = *(const bf16x8*)(p + LO_OFF);
    int off = (nb3 * 32 + a) * 256 + kbase;
    bf16x8 wh = *(const bf16x8*)(g_w3h + off);
    bf16x8 wl = *(const bf16x8*)(g_w3l + off);
    acc3 = MFMA32(wh, bh, acc3);
    acc3 = MFMA32(wh, bl, acc3);
    acc3 = MFMA32(wl, bh, acc3);
  }
  __syncthreads(); // h dead; region becomes params P0 (floats 0..) / P1 (2176..)
#pragma unroll
  for (int r2 = 0; r2 < 4; ++r2) {
    f32x4 run = {acc3[r2 * 4], acc3[r2 * 4 + 1], acc3[r2 * 4 + 2], acc3[r2 * 4 + 3]};
    *(f32x4*)(ldsf + kh * 2176 + a * 68 + nb3 * 32 + r2 * 8 + hf * 4) = run;
  }
  __syncthreads();

  // Phase G: epilogue. Lane j owns output col j; 8 rows per wave. Output
  // permutation via shfl (out col j takes y[perm[j]]).
  const float sg = g_sgls;
  const int pj = perm[lane];
  const float eg = g_egls[lane];
  const float go = goff[lane];
  const int cb = lane & 31;
#pragma unroll
  for (int rr = 0; rr < 8; ++rr) {
    int r = wave * 8 + rr;
    float pls = ldsf[r * 68 + cb]      + ldsf[2176 + r * 68 + cb];
    float pof = ldsf[r * 68 + 32 + cb] + ldsf[2176 + r * 68 + 32 + cb];
    float ls = 2.0f * fast_tanh(0.1f * pls);
    float y = (lane < 32) ? xreg[rr] : (xreg[rr] * __expf(ls) + pof);
    float z = y * eg + go;
    float zf = __shfl(z, pj);
    out[(row0 + r) * DD + lane] = zf;
    float v = (lane < 32) ? ls : 0.0f;
    v += __shfl_xor(v, 1); v += __shfl_xor(v, 2); v += __shfl_xor(v, 4);
    v += __shfl_xor(v, 8); v += __shfl_xor(v, 16);
    if (lane == 0) out[(size_t)NB * DD + row0 + r] = v + sg;
  }
}

extern "C" void kernel_launch(void* const* d_in, const int* in_sizes, int n_in,
                              void* d_out, int out_size, void* d_ws, size_t ws_size,
                              hipStream_t stream) {
  const float* x    = (const float*)d_in[0];
  const int*   perm = (const int*)d_in[1];
  const float* W1   = (const float*)d_in[2];
  const float* b1   = (const float*)d_in[3];
  const float* W2   = (const float*)d_in[4];
  const float* b2   = (const float*)d_in[5];
  const float* W3   = (const float*)d_in[6];
  const float* b3   = (const float*)d_in[7];
  const float* gls  = (const float*)d_in[8];
  const float* goff = (const float*)d_in[9];
  (void)in_sizes; (void)n_in; (void)d_ws; (void)ws_size; (void)out_size;

  flow_prep<<<25, 256, 0, stream>>>(W1, W2, W3, perm, gls);
  flow_main<<<NB / 32, 256, 0, stream>>>(x, perm, b1, b2, b3, goff, (float*)d_out);
}

// Round 7
// 219.708 us; speedup vs baseline: 1.3794x; 1.3794x over previous
//
#include <hip/hip_runtime.h>

// AllInOneFlow: y = perm-scatter( scale * concat(x1, x2*exp(ls)+off) + goff ), log_jac
// MLP 32->256->256->64 (gelu,gelu,linear), B=131072. bf16-split (3-product) MFMA 16x16x32.
// This rev: round-4 structure (64 rows, 8 waves, 64KiB LDS) + explicit register
// double-buffer prefetch of weight fragments (kill L2-latency stalls) + setprio
// around MFMA clusters + shfl-based permuted epilogue (no LDS round-trip).

#define NB  131072
#define DD  64
#define HH  256

typedef float f32x4 __attribute__((ext_vector_type(4)));
typedef short bf16x8 __attribute__((ext_vector_type(8)));
typedef unsigned short u16;
typedef unsigned int u32;
typedef u32 u32x2 __attribute__((ext_vector_type(2)));

__device__ __align__(16) u16 g_w1h[32 * 256],  g_w1l[32 * 256];   // [n][k] n<256,k<32
__device__ __align__(16) u16 g_w2h[256 * 256], g_w2l[256 * 256];  // [n][k] 256x256
__device__ __align__(16) u16 g_w3h[64 * 256],  g_w3l[64 * 256];   // [n][k] n<64,k<256
__device__ __align__(16) int g_invp[64];
__device__ float g_egls[64];
__device__ float g_sgls;

__device__ __forceinline__ u16 f2bf(float x) {
  u32 u = __float_as_uint(x);
  u32 r = u + 0x7FFFu + ((u >> 16) & 1u); // RNE
  return (u16)(r >> 16);
}
__device__ __forceinline__ float bf2f(u16 b) {
  return __uint_as_float(((u32)b) << 16);
}
__device__ __forceinline__ u32 pk2(float a, float b) { // packed 2x f32->bf16 RNE
  u32 r;
  asm("v_cvt_pk_bf16_f32 %0, %1, %2" : "=v"(r) : "v"(a), "v"(b));
  return r;
}
__device__ __forceinline__ float fast_tanh(float z) {
  float e = __expf(2.0f * z);
  return 1.0f - 2.0f * __builtin_amdgcn_rcpf(e + 1.0f);
}
__device__ __forceinline__ float gelu_tanh(float x) {
  float u = x * x;
  float inner = x * (0.7978845608028654f + 0.03567740814183556f * u);
  return 0.5f * x * (1.0f + fast_tanh(inner));
}
__device__ __forceinline__ void split8(const float* v, bf16x8& hi, bf16x8& lo) {
  u32* hw = (u32*)&hi; u32* lw = (u32*)&lo;
#pragma unroll
  for (int j = 0; j < 4; ++j) {
    float a = v[2 * j], b = v[2 * j + 1];
    u32 p = pk2(a, b);
    float la = a - __uint_as_float(p << 16);
    float lb = b - __uint_as_float(p & 0xffff0000u);
    hw[j] = p; lw[j] = pk2(la, lb);
  }
}

#define MFMA(a, b, c) __builtin_amdgcn_mfma_f32_16x16x32_bf16((a), (b), (c), 0, 0, 0)
#define LO_OFF 16384  // u16 offset of lo array (+32 KiB); h_hi is 64x256 u16

// gelu + split-once + b64 stores of 4 consecutive n at row m (hi and lo arrays).
// XOR swizzle on n (bits 3-5 ^ m&7); same involution applied on k at read time.
__device__ __forceinline__ void store_h4(u16* hb, int m, int n0, f32x4 accv) {
  float g0 = gelu_tanh(accv[0]), g1 = gelu_tanh(accv[1]);
  float g2 = gelu_tanh(accv[2]), g3 = gelu_tanh(accv[3]);
  u32 h01 = pk2(g0, g1), h23 = pk2(g2, g3);
  float l0 = g0 - __uint_as_float(h01 << 16);
  float l1 = g1 - __uint_as_float(h01 & 0xffff0000u);
  float l2 = g2 - __uint_as_float(h23 << 16);
  float l3 = g3 - __uint_as_float(h23 & 0xffff0000u);
  u32 l01 = pk2(l0, l1), l23 = pk2(l2, l3);
  int idx = (m << 8) + (n0 ^ ((m & 7) << 3));
  *(u32x2*)(hb + idx) = u32x2{h01, h23};
  *(u32x2*)(hb + idx + LO_OFF) = u32x2{l01, l23};
}

// ---------------- prep: LDS-tiled transpose, coalesced both sides ----------------
__global__ void flow_prep(const float* __restrict__ W1, const float* __restrict__ W2,
                          const float* __restrict__ W3, const int* __restrict__ perm,
                          const float* __restrict__ gin) {
  __shared__ float t[64][65];
  const int b = blockIdx.x, tid = threadIdx.x;
  if (b < 16) { // W2 [256k][256n]: tile kt,nt of 64x64
    int kt = (b & 3) * 64, nt = (b >> 2) * 64;
#pragma unroll
    for (int it = 0; it < 16; ++it) {
      int idx = it * 256 + tid, r = idx >> 6, c = idx & 63;
      t[r][c] = W2[(kt + r) * 256 + nt + c];
    }
    __syncthreads();
#pragma unroll
    for (int it = 0; it < 16; ++it) {
      int idx = it * 256 + tid, cc = idx >> 6, rr = idx & 63;
      float v = t[rr][cc];
      u16 h = f2bf(v);
      g_w2h[(nt + cc) * 256 + kt + rr] = h;
      g_w2l[(nt + cc) * 256 + kt + rr] = f2bf(v - bf2f(h));
    }
  } else if (b < 20) { // W1 [32k][256n]: n-tile of 64
    int nt = (b - 16) * 64;
#pragma unroll
    for (int it = 0; it < 8; ++it) {
      int idx = it * 256 + tid, r = idx >> 6, c = idx & 63;
      t[r][c] = W1[r * 256 + nt + c];
    }
    __syncthreads();
#pragma unroll
    for (int it = 0; it < 8; ++it) {
      int idx = it * 256 + tid, cc = idx >> 5, rr = idx & 31;
      float v = t[rr][cc];
      u16 h = f2bf(v);
      g_w1h[(nt + cc) * 32 + rr] = h;
      g_w1l[(nt + cc) * 32 + rr] = f2bf(v - bf2f(h));
    }
  } else if (b < 24) { // W3 [256k][64n]: k-tile of 64
    int kt = (b - 20) * 64;
#pragma unroll
    for (int it = 0; it < 16; ++it) {
      int idx = it * 256 + tid, r = idx >> 6, c = idx & 63;
      t[r][c] = W3[(kt + r) * 64 + c];
    }
    __syncthreads();
#pragma unroll
    for (int it = 0; it < 16; ++it) {
      int idx = it * 256 + tid, cc = idx >> 6, rr = idx & 63;
      float v = t[rr][cc];
      u16 h = f2bf(v);
      g_w3h[cc * 256 + kt + rr] = h;
      g_w3l[cc * 256 + kt + rr] = f2bf(v - bf2f(h));
    }
  } else { // perm, inv perm, global scale
    if (tid < 64) {
      int tt = tid;
      g_invp[perm[tt]] = tt;
      float gl = 4.0f * tanhf(gin[tt] * 0.25f);
      g_egls[tt] = expf(gl);
      float s = gl;
#pragma unroll
      for (int m = 1; m < 64; m <<= 1) s += __shfl_xor(s, m);
      if (tt == 0) g_sgls = s;
    }
  }
}

// ---------------- main: 64 rows/block, 8 waves; waves split N ----------------
// LDS 64 KiB: h_hi bf16[64][256] at 0, h_lo at +32KB; x-stage / params overlay
// (f32, stride 68). MFMA A = weight [n][k], B = activation [k][m] -> D[n][m]:
// thread (g,lm) holds rows n = g*4+{0..3}, col m = lm (per m89 C/D map).
__global__ __launch_bounds__(512, 4) void flow_main(
    const float* __restrict__ x, const int* __restrict__ perm,
    const float* __restrict__ b1, const float* __restrict__ b2,
    const float* __restrict__ b3, const float* __restrict__ goff,
    float* __restrict__ out) {
  __shared__ u32 lds32[16384]; // 64 KiB exactly -> 2 blocks/CU
  u16* hb = (u16*)lds32;
  float* ldsf = (float*)lds32;
  const int tid = threadIdx.x;
  const int wave = tid >> 6, lane = tid & 63;
  const int g = lane >> 4, lm = lane & 15;
  const size_t row0 = (size_t)blockIdx.x * 64;

  // Phase A: stage x (64x64 f32), stride 68; GEMM1 weights prefetch in parallel
  {
    const float4* xv = (const float4*)(x + row0 * DD);
#pragma unroll
    for (int t = 0; t < 2; ++t) {
      int i = tid + t * 512;
      int r = i >> 4, c4 = i & 15;
      float4 v = xv[i];
      *(float4*)(ldsf + r * 68 + c4 * 4) = v;
    }
  }
  bf16x8 w1hv[2], w1lv[2];
  f32x4 b1v[2], b2v[2];
#pragma unroll
  for (int c = 0; c < 2; ++c) {
    int nt = wave * 2 + c;
    w1hv[c] = *(const bf16x8*)(g_w1h + (nt * 16 + lm) * 32 + g * 8);
    w1lv[c] = *(const bf16x8*)(g_w1l + (nt * 16 + lm) * 32 + g * 8);
    b1v[c] = *(const f32x4*)(b1 + nt * 16 + g * 4);
    b2v[c] = *(const f32x4*)(b2 + nt * 16 + g * 4);
  }
  __syncthreads();

  // Phase B: inverse-perm gather -> GEMM1 B-fragments (activations), plus
  // epilogue x regs (lane j owns final pre-perm col j for its wave's 8 rows).
  int ic[8];
#pragma unroll
  for (int j = 0; j < 8; ++j) ic[j] = g_invp[g * 8 + j];
  bf16x8 bxh[4], bxl[4]; // B-frag: [k = g*8+j][m = mt*16+lm]
#pragma unroll
  for (int mt = 0; mt < 4; ++mt) {
    float v[8];
#pragma unroll
    for (int j = 0; j < 8; ++j) v[j] = ldsf[(mt * 16 + lm) * 68 + ic[j]];
    split8(v, bxh[mt], bxl[mt]);
  }
  float xreg[8];
  {
    int cj = g_invp[lane];
#pragma unroll
    for (int rr = 0; rr < 8; ++rr) xreg[rr] = ldsf[(wave * 8 + rr) * 68 + cj];
  }
  __syncthreads(); // x-stage dead; region becomes h_hi/h_lo

  // Phase C: GEMM1 (K=32). Wave owns n-tiles {2w, 2w+1}; weights pre-loaded.
#pragma unroll
  for (int c = 0; c < 2; ++c) {
    int nt = wave * 2 + c;
    __builtin_amdgcn_s_setprio(1);
    f32x4 acc[4];
#pragma unroll
    for (int mt = 0; mt < 4; ++mt) {
      acc[mt] = b1v[c];
      acc[mt] = MFMA(w1hv[c], bxh[mt], acc[mt]);
      acc[mt] = MFMA(w1hv[c], bxl[mt], acc[mt]);
      acc[mt] = MFMA(w1lv[c], bxh[mt], acc[mt]);
    }
    __builtin_amdgcn_s_setprio(0);
#pragma unroll
    for (int mt = 0; mt < 4; ++mt)
      store_h4(hb, mt * 16 + lm, nt * 16 + g * 4, acc[mt]);
  }
  __syncthreads();

  // Phase D: GEMM2 (K=256). Weight frags double-buffer-prefetched (1-deep);
  // B-frags (h1) from LDS b128, no unpack.
  f32x4 acc2[2][4];
#pragma unroll
  for (int c = 0; c < 2; ++c)
#pragma unroll
    for (int mt = 0; mt < 4; ++mt) acc2[c][mt] = b2v[c];
  const int swz = (lm & 7) << 3;
  bf16x8 pwh[2][2], pwl[2][2];
#pragma unroll
  for (int c = 0; c < 2; ++c) {
    int off = ((wave * 2 + c) * 16 + lm) * 256 + g * 8;
    pwh[0][c] = *(const bf16x8*)(g_w2h + off);
    pwl[0][c] = *(const bf16x8*)(g_w2l + off);
  }
#pragma unroll
  for (int kk = 0; kk < 8; ++kk) {
    const int cur = kk & 1;
    if (kk < 7) {
#pragma unroll
      for (int c = 0; c < 2; ++c) {
        int off = ((wave * 2 + c) * 16 + lm) * 256 + (kk + 1) * 32 + g * 8;
        pwh[cur ^ 1][c] = *(const bf16x8*)(g_w2h + off);
        pwl[cur ^ 1][c] = *(const bf16x8*)(g_w2l + off);
      }
    }
    int koff = (kk * 32 + g * 8) ^ swz;
    bf16x8 bh[4], bl[4];
#pragma unroll
    for (int mt = 0; mt < 4; ++mt) {
      const u16* p = hb + ((mt * 16 + lm) << 8) + koff;
      bh[mt] = *(const bf16x8*)p;
      bl[mt] = *(const bf16x8*)(p + LO_OFF);
    }
    __builtin_amdgcn_s_setprio(1);
#pragma unroll
    for (int c = 0; c < 2; ++c)
#pragma unroll
      for (int mt = 0; mt < 4; ++mt) {
        acc2[c][mt] = MFMA(pwh[cur][c], bh[mt], acc2[c][mt]);
        acc2[c][mt] = MFMA(pwh[cur][c], bl[mt], acc2[c][mt]);
        acc2[c][mt] = MFMA(pwl[cur][c], bh[mt], acc2[c][mt]);
      }
    __builtin_amdgcn_s_setprio(0);
  }
  // GEMM3 kk=0 weight + bias preload (no LDS dependency; in flight over barrier)
  const int ct3 = wave & 3, rtb = (wave >> 2) * 2;
  bf16x8 p3h[2], p3l[2];
  p3h[0] = *(const bf16x8*)(g_w3h + (ct3 * 16 + lm) * 256 + g * 8);
  p3l[0] = *(const bf16x8*)(g_w3l + (ct3 * 16 + lm) * 256 + g * 8);
  f32x4 b3v = *(const f32x4*)(b3 + ct3 * 16 + g * 4);
  __syncthreads(); // all h1 reads done before overwrite
#pragma unroll
  for (int c = 0; c < 2; ++c)
#pragma unroll
    for (int mt = 0; mt < 4; ++mt)
      store_h4(hb, mt * 16 + lm, (wave * 2 + c) * 16 + g * 4, acc2[c][mt]);
  __syncthreads();

  // Phase F: GEMM3 (K=256, N=64). Wave: n-tile ct3, m-tiles {rtb, rtb+1};
  // weight frags double-buffer-prefetched.
  f32x4 acc3[2];
  acc3[0] = b3v; acc3[1] = b3v;
#pragma unroll
  for (int kk = 0; kk < 8; ++kk) {
    const int cur = kk & 1;
    if (kk < 7) {
      int off = (ct3 * 16 + lm) * 256 + (kk + 1) * 32 + g * 8;
      p3h[cur ^ 1] = *(const bf16x8*)(g_w3h + off);
      p3l[cur ^ 1] = *(const bf16x8*)(g_w3l + off);
    }
    int koff = (kk * 32 + g * 8) ^ swz;
    bf16x8 bh[2], bl[2];
#pragma unroll
    for (int q = 0; q < 2; ++q) {
      const u16* p = hb + (((rtb + q) * 16 + lm) << 8) + koff;
      bh[q] = *(const bf16x8*)p;
      bl[q] = *(const bf16x8*)(p + LO_OFF);
    }
    __builtin_amdgcn_s_setprio(1);
#pragma unroll
    for (int q = 0; q < 2; ++q) {
      acc3[q] = MFMA(p3h[cur], bh[q], acc3[q]);
      acc3[q] = MFMA(p3h[cur], bl[q], acc3[q]);
      acc3[q] = MFMA(p3l[cur], bh[q], acc3[q]);
    }
    __builtin_amdgcn_s_setprio(0);
  }
  __syncthreads(); // all h2 reads done; region becomes params (f32, stride 68)
#pragma unroll
  for (int q = 0; q < 2; ++q)
    *(f32x4*)(ldsf + ((rtb + q) * 16 + lm) * 68 + ct3 * 16 + g * 4) = acc3[q];
  __syncthreads();

  // Phase G: epilogue. Lane j owns pre-perm col j; 8 rows per wave. Output
  // permutation via shfl (out col j takes y[perm[j]]).
  const float sg = g_sgls;
  const int pj = perm[lane];
  const float eg = g_egls[lane];
  const float go = goff[lane];
  const int cb = lane & 31;
#pragma unroll
  for (int rr = 0; rr < 8; ++rr) {
    int r = wave * 8 + rr;
    float pls = ldsf[r * 68 + cb];
    float pof = ldsf[r * 68 + 32 + cb];
    float ls = 2.0f * fast_tanh(0.1f * pls);
    float y = (lane < 32) ? xreg[rr] : (xreg[rr] * __expf(ls) + pof);
    float z = y * eg + go;
    float zf = __shfl(z, pj);
    out[(row0 + r) * DD + lane] = zf;
    float v = (lane < 32) ? ls : 0.0f;
    v += __shfl_xor(v, 1); v += __shfl_xor(v, 2); v += __shfl_xor(v, 4);
    v += __shfl_xor(v, 8); v += __shfl_xor(v, 16);
    if (lane == 0) out[(size_t)NB * DD + row0 + r] = v + sg;
  }
}

extern "C" void kernel_launch(void* const* d_in, const int* in_sizes, int n_in,
                              void* d_out, int out_size, void* d_ws, size_t ws_size,
                              hipStream_t stream) {
  const float* x    = (const float*)d_in[0];
  const int*   perm = (const int*)d_in[1];
  const float* W1   = (const float*)d_in[2];
  const float* b1   = (const float*)d_in[3];
  const float* W2   = (const float*)d_in[4];
  const float* b2   = (const float*)d_in[5];
  const float* W3   = (const float*)d_in[6];
  const float* b3   = (const float*)d_in[7];
  const float* gls  = (const float*)d_in[8];
  const float* goff = (const float*)d_in[9];
  (void)in_sizes; (void)n_in; (void)d_ws; (void)ws_size; (void)out_size;

  flow_prep<<<25, 256, 0, stream>>>(W1, W2, W3, perm, gls);
  flow_main<<<NB / 64, 512, 0, stream>>>(x, perm, b1, b2, b3, goff, (float*)d_out);
}